// Round 10
// baseline (1247.466 us; speedup 1.0000x reference)
//
#include <hip/hip_runtime.h>
#include <hip/hip_bf16.h>

typedef __bf16 bf16;
typedef __bf16 bf16x8 __attribute__((ext_vector_type(8)));
typedef float f32x4 __attribute__((ext_vector_type(4)));
typedef unsigned int u32x4 __attribute__((ext_vector_type(4)));

#define B_SZ 32
#define T_SZ 64
#define H_SZ 512
#define V_SZ 32000

__device__ __forceinline__ float sigmoidf_(float v) { return 1.0f / (1.0f + expf(-v)); }

__device__ __forceinline__ bf16x8 cvt8(const float* __restrict__ p) {
  float4 a = *(const float4*)p;
  float4 b = *(const float4*)(p + 4);
  bf16x8 o;
  o[0] = (bf16)a.x; o[1] = (bf16)a.y; o[2] = (bf16)a.z; o[3] = (bf16)a.w;
  o[4] = (bf16)b.x; o[5] = (bf16)b.y; o[6] = (bf16)b.z; o[7] = (bf16)b.w;
  return o;
}

// ---- LLC-coherent primitives (bypass L1/L2 via sc0 sc1) ----
#define GLD(dst, base, off) \
  asm volatile("global_load_dwordx4 %0, %1, off offset:" off " sc0 sc1" \
               : "=v"(dst) : "v"(base))
#define GST2(base, off, val) do { \
  unsigned int w_ = (unsigned int)__builtin_bit_cast(unsigned short, (bf16)(val)); \
  asm volatile("global_store_short %0, %1, off offset:" off " sc0 sc1" \
               :: "v"(base), "v"(w_) : "memory"); \
} while (0)
#define WAITV  asm volatile("s_waitcnt vmcnt(0)" ::: "memory")
#define SCHEDB __builtin_amdgcn_sched_barrier(0)

// ---------------- prep: h0 init, flags, Wz/Wr/Wh h-part extract+cvt ----------------
__global__ void prep_k(const float* __restrict__ feat, bf16* __restrict__ h_g,
                       int* __restrict__ ctr,
                       const float* __restrict__ Wz, const float* __restrict__ Wr,
                       const float* __restrict__ Wh, bf16* __restrict__ dst) {
  int i = blockIdx.x * blockDim.x + threadIdx.x;   // 98304 threads
  int w = i >> 15;
  int rem = i & 32767;
  int n = rem >> 6;
  int k8 = (rem & 63) * 8;
  const float* W = (w == 0) ? Wz : (w == 1) ? Wr : Wh;
  *(bf16x8*)(dst + (long)w * 262144 + n * 512 + k8) = cvt8(W + (long)n * 1024 + 512 + k8);
  if (i < B_SZ * H_SZ) h_g[i] = (bf16)feat[i];
  if (i < 128) ctr[i] = 0;
}

// ---------------- 128x128 bf16-MFMA GEMM-BT: C = A @ B^T + bias (f32 out) ----------------
template<int AMODE, bool BF32>
__global__ __launch_bounds__(256) void gemm_bt(
    const void* __restrict__ Av, const int* __restrict__ caps, const float* __restrict__ emb,
    const void* __restrict__ B0, const void* __restrict__ B1, const void* __restrict__ B2, int ldb,
    const float* __restrict__ bias0, const float* __restrict__ bias1, const float* __restrict__ bias2,
    float* __restrict__ C, long ldc, int K, int mtiles,
    int gemm_blocks, const float* __restrict__ fcw_src, bf16* __restrict__ fcw_dst)
{
  __shared__ __align__(16) bf16 lA[128 * 32];
  __shared__ __align__(16) bf16 lB[128 * 32];
  const int tid  = threadIdx.x;

  if (AMODE == 1 && (int)blockIdx.x >= gemm_blocks) {   // fused fc_w cvt blocks
    long base = ((long)(blockIdx.x - gemm_blocks) * 256 + tid) * 8;
    const long stride = (long)128 * 256 * 8;
    for (long i = base; i < (long)V_SZ * H_SZ; i += stride)
      *(bf16x8*)(fcw_dst + i) = cvt8(fcw_src + i);
    return;
  }

  const int lane = tid & 63;
  const int l15  = lane & 15;
  const int kb8  = (lane >> 4) * 8;
  const int wid  = tid >> 6;
  const int wm   = wid >> 1, wn = wid & 1;
  const int wg   = blockIdx.x;
  const int mtile = wg % mtiles, ntile = wg / mtiles;
  const int m0 = mtile * 128, n0 = ntile * 128;

  const void* Bv; const float* bias; int nb;
  if (AMODE == 1) {
    int wsel = n0 >> 9;
    Bv = wsel == 0 ? B0 : wsel == 1 ? B1 : B2;
    bias = wsel == 0 ? bias0 : wsel == 1 ? bias1 : bias2;
    nb = n0 & 511;
  } else { Bv = B0; bias = bias0; nb = n0; }

  f32x4 acc[4][4] = {};

  for (int k0 = 0; k0 < K; k0 += 32) {
    #pragma unroll
    for (int j = 0; j < 2; ++j) {
      int c = j * 256 + tid;          // 0..511
      int row = c >> 2;
      int kc = (c & 3) * 8;
      bf16x8 av;
      if (AMODE == 1) av = cvt8(emb + (long)caps[m0 + row] * K + k0 + kc);
      else            av = *(const bf16x8*)((const bf16*)Av + (long)(m0 + row) * K + k0 + kc);
      *(bf16x8*)&lA[row * 32 + kc] = av;
      bf16x8 bv;
      if (BF32) bv = cvt8((const float*)Bv + (long)(nb + row) * ldb + k0 + kc);
      else      bv = *(const bf16x8*)((const bf16*)Bv + (long)(nb + row) * ldb + k0 + kc);
      *(bf16x8*)&lB[row * 32 + kc] = bv;
    }
    __syncthreads();
    bf16x8 af[4], bfr[4];
    #pragma unroll
    for (int mf = 0; mf < 4; ++mf)
      af[mf] = *(const bf16x8*)&lA[(wm * 64 + mf * 16 + l15) * 32 + kb8];
    #pragma unroll
    for (int nf = 0; nf < 4; ++nf)
      bfr[nf] = *(const bf16x8*)&lB[(wn * 64 + nf * 16 + l15) * 32 + kb8];
    #pragma unroll
    for (int mf = 0; mf < 4; ++mf)
      #pragma unroll
      for (int nf = 0; nf < 4; ++nf)
        acc[mf][nf] = __builtin_amdgcn_mfma_f32_16x16x32_bf16(af[mf], bfr[nf], acc[mf][nf], 0, 0, 0);
    __syncthreads();
  }

  #pragma unroll
  for (int mf = 0; mf < 4; ++mf)
    #pragma unroll
    for (int nf = 0; nf < 4; ++nf)
      #pragma unroll
      for (int r = 0; r < 4; ++r) {
        int row = m0 + wm * 64 + mf * 16 + (lane >> 4) * 4 + r;
        int lc  = wn * 64 + nf * 16 + l15;
        C[(long)row * ldc + n0 + lc] = acc[mf][nf][r] + bias[nb + lc];
      }
}

// ---------------- persistent GRU recurrence: 8 wgs x 256 thr, dual-chain interleave ----
// Wave w=tid>>6; col-owner u=bid*4+w owns cols u*16..+15 for BOTH batch-halves
// (g0 rows 0-15, g1 rows 16-31) which form two INDEPENDENT dependency chains.
// While one chain waits at its barrier, the wave computes the other chain's phase.
// Barrier = R4-proven: RELAXED agent fetch_add arrival + RELAXED atomic poll + s_sleep.
__global__ __launch_bounds__(256, 2) void gru_rec(
    const float* __restrict__ X,        // [2048][1536] z|r|h x-preactivations (bias folded)
    const bf16* __restrict__ Wzh, const bf16* __restrict__ Wrh, const bf16* __restrict__ Whh,
    const float* __restrict__ feat,
    bf16* __restrict__ h_g, bf16* __restrict__ rh_g,
    bf16* __restrict__ hs, int* __restrict__ ctr)
{
  __shared__ __align__(16) char ldsb[32768];      // two 16KB tiles (g0, g1), XOR-swizzled
  const int tid  = threadIdx.x;                   // 0..255
  const int lane = tid & 63;
  const int u    = blockIdx.x * 4 + (tid >> 6);   // col-owner 0..31
  const int l15  = lane & 15;
  const int kb   = (lane >> 4) * 8;
  const int rq   = (lane >> 4) * 4;
  const int gcol = u * 16 + l15;

  int* c0 = ctr;
  int* c1 = ctr + 64;

  const bf16* wz = Wzh + (long)gcol * 512 + kb;
  const bf16* wr = Wrh + (long)gcol * 512 + kb;
  const bf16* wh = Whh + (long)gcol * 512 + kb;

  // wave-private h state for both groups
  float hp0[4], hp1[4];
  #pragma unroll
  for (int r = 0; r < 4; ++r) {
    hp0[r] = feat[(rq + r) * 512 + gcol];
    hp1[r] = feat[(16 + rq + r) * 512 + gcol];
  }

  const float* xb0 = X + (long)rq * 98304 + gcol;          // rows 0-15 base
  const float* xb1 = X + (long)(16 + rq) * 98304 + gcol;   // rows 16-31 base
  float xz0[4], xr0[4], xz1[4], xr1[4];
  #pragma unroll
  for (int r = 0; r < 4; ++r) {
    xz0[r] = xb0[r * 98304];          xr0[r] = xb0[r * 98304 + 512];
    xz1[r] = xb1[r * 98304];          xr1[r] = xb1[r * 98304 + 512];
  }

  // LDS staging: 256 thr x 64B; row = tid>>4
  const bf16* hsrc0  = h_g  + tid * 32;
  const bf16* hsrc1  = h_g  + 8192 + tid * 32;
  const bf16* rhsrc0 = rh_g + tid * 32;
  const bf16* rhsrc1 = rh_g + 8192 + tid * 32;
  const int wswz = ((tid >> 4) & 7) << 4;
  const int wo0 = (tid * 64 +  0) ^ wswz;
  const int wo1 = (tid * 64 + 16) ^ wswz;
  const int wo2 = (tid * 64 + 32) ^ wswz;
  const int wo3 = (tid * 64 + 48) ^ wswz;
  const int fb  = (l15 * 1024 + (lane >> 4) * 16) ^ ((l15 & 7) << 4);

  bf16* rhst0 = rh_g + rq * 512 + gcol;
  bf16* rhst1 = rh_g + 8192 + rq * 512 + gcol;
  bf16* hst0  = h_g  + rq * 512 + gcol;
  bf16* hst1  = h_g  + 8192 + rq * 512 + gcol;
  bf16* hsst0 = hs + (long)rq * 32768 + gcol;
  bf16* hsst1 = hs + (long)(16 + rq) * 32768 + gcol;

#define STAGE(ldsoff, src) do { \
    u32x4 s0_, s1_, s2_, s3_; \
    GLD(s0_, src, "0"); GLD(s1_, src, "16"); GLD(s2_, src, "32"); GLD(s3_, src, "48"); \
    WAITV; SCHEDB; \
    *(u32x4*)(ldsb + (ldsoff) + wo0) = s0_; *(u32x4*)(ldsb + (ldsoff) + wo1) = s1_; \
    *(u32x4*)(ldsb + (ldsoff) + wo2) = s2_; *(u32x4*)(ldsb + (ldsoff) + wo3) = s3_; \
  } while (0)

#define ARR(c) do { if (tid == 0) \
    __hip_atomic_fetch_add((c), 1, __ATOMIC_RELAXED, __HIP_MEMORY_SCOPE_AGENT); } while (0)
#define POLL1(c, tg) do { \
    if (tid == 0) { \
      while (__hip_atomic_load((c), __ATOMIC_RELAXED, __HIP_MEMORY_SCOPE_AGENT) < (tg)) \
        __builtin_amdgcn_s_sleep(1); \
    } \
    __syncthreads(); \
  } while (0)

  int ep0 = 0, ep1 = 0;
  float zf0[4], zf1[4], xh0[4], xh1[4];

  for (int t = 0; t < T_SZ; ++t) {
    // ============ P1 g0: z0 (regs) + r0 -> rh0 ============
    STAGE(0, hsrc0);
    __syncthreads();
    {
      f32x4 ze = {}, zo = {}, re = {}, ro = {};
      #pragma unroll
      for (int kk = 0; kk < 16; kk += 2) {
        bf16x8 a0 = *(const bf16x8*)(ldsb + (fb ^ (kk * 64)));
        bf16x8 a1 = *(const bf16x8*)(ldsb + (fb ^ ((kk + 1) * 64)));
        bf16x8 bz0 = *(const bf16x8*)(wz + kk * 32);
        bf16x8 br0 = *(const bf16x8*)(wr + kk * 32);
        bf16x8 bz1 = *(const bf16x8*)(wz + (kk + 1) * 32);
        bf16x8 br1 = *(const bf16x8*)(wr + (kk + 1) * 32);
        ze = __builtin_amdgcn_mfma_f32_16x16x32_bf16(a0, bz0, ze, 0, 0, 0);
        re = __builtin_amdgcn_mfma_f32_16x16x32_bf16(a0, br0, re, 0, 0, 0);
        zo = __builtin_amdgcn_mfma_f32_16x16x32_bf16(a1, bz1, zo, 0, 0, 0);
        ro = __builtin_amdgcn_mfma_f32_16x16x32_bf16(a1, br1, ro, 0, 0, 0);
      }
      GST2(rhst0, "0",    sigmoidf_(re[0] + ro[0] + xr0[0]) * hp0[0]);
      GST2(rhst0, "1024", sigmoidf_(re[1] + ro[1] + xr0[1]) * hp0[1]);
      GST2(rhst0, "2048", sigmoidf_(re[2] + ro[2] + xr0[2]) * hp0[2]);
      GST2(rhst0, "3072", sigmoidf_(re[3] + ro[3] + xr0[3]) * hp0[3]);
      WAITV;
      __syncthreads();
      ++ep0; ARR(c0);
      #pragma unroll
      for (int r = 0; r < 4; ++r) zf0[r] = sigmoidf_(ze[r] + zo[r] + xz0[r]);
      #pragma unroll
      for (int r = 0; r < 4; ++r) xh0[r] = xb0[r * 98304 + t * 1536 + 1024];
    }

    // ============ P1 g1: z1 + r1 -> rh1 (hides g0 barrier latency) ============
    STAGE(16384, hsrc1);
    __syncthreads();
    {
      f32x4 ze = {}, zo = {}, re = {}, ro = {};
      #pragma unroll
      for (int kk = 0; kk < 16; kk += 2) {
        bf16x8 a0 = *(const bf16x8*)(ldsb + 16384 + (fb ^ (kk * 64)));
        bf16x8 a1 = *(const bf16x8*)(ldsb + 16384 + (fb ^ ((kk + 1) * 64)));
        bf16x8 bz0 = *(const bf16x8*)(wz + kk * 32);
        bf16x8 br0 = *(const bf16x8*)(wr + kk * 32);
        bf16x8 bz1 = *(const bf16x8*)(wz + (kk + 1) * 32);
        bf16x8 br1 = *(const bf16x8*)(wr + (kk + 1) * 32);
        ze = __builtin_amdgcn_mfma_f32_16x16x32_bf16(a0, bz0, ze, 0, 0, 0);
        re = __builtin_amdgcn_mfma_f32_16x16x32_bf16(a0, br0, re, 0, 0, 0);
        zo = __builtin_amdgcn_mfma_f32_16x16x32_bf16(a1, bz1, zo, 0, 0, 0);
        ro = __builtin_amdgcn_mfma_f32_16x16x32_bf16(a1, br1, ro, 0, 0, 0);
      }
      GST2(rhst1, "0",    sigmoidf_(re[0] + ro[0] + xr1[0]) * hp1[0]);
      GST2(rhst1, "1024", sigmoidf_(re[1] + ro[1] + xr1[1]) * hp1[1]);
      GST2(rhst1, "2048", sigmoidf_(re[2] + ro[2] + xr1[2]) * hp1[2]);
      GST2(rhst1, "3072", sigmoidf_(re[3] + ro[3] + xr1[3]) * hp1[3]);
      WAITV;
      __syncthreads();
      ++ep1; ARR(c1);
      #pragma unroll
      for (int r = 0; r < 4; ++r) zf1[r] = sigmoidf_(ze[r] + zo[r] + xz1[r]);
      #pragma unroll
      for (int r = 0; r < 4; ++r) xh1[r] = xb1[r * 98304 + t * 1536 + 1024];
    }

    // ============ P2 g0: h_tilde + blend ============
    POLL1(c0, 8 * ep0);
    STAGE(0, rhsrc0);
    __syncthreads();
    {
      f32x4 he = {}, ho = {};
      #pragma unroll
      for (int kk = 0; kk < 16; kk += 2) {
        bf16x8 a0 = *(const bf16x8*)(ldsb + (fb ^ (kk * 64)));
        bf16x8 a1 = *(const bf16x8*)(ldsb + (fb ^ ((kk + 1) * 64)));
        bf16x8 bh0 = *(const bf16x8*)(wh + kk * 32);
        bf16x8 bh1 = *(const bf16x8*)(wh + (kk + 1) * 32);
        he = __builtin_amdgcn_mfma_f32_16x16x32_bf16(a0, bh0, he, 0, 0, 0);
        ho = __builtin_amdgcn_mfma_f32_16x16x32_bf16(a1, bh1, ho, 0, 0, 0);
      }
      #pragma unroll
      for (int r = 0; r < 4; ++r) {
        float ht = tanhf(he[r] + ho[r] + xh0[r]);
        hp0[r] = hp0[r] + zf0[r] * (ht - hp0[r]);
      }
      if (t + 1 < T_SZ) {
        GST2(hst0, "0", hp0[0]); GST2(hst0, "1024", hp0[1]);
        GST2(hst0, "2048", hp0[2]); GST2(hst0, "3072", hp0[3]);
        WAITV;
        __syncthreads();
        ++ep0; ARR(c0);
      }
      #pragma unroll
      for (int r = 0; r < 4; ++r) hsst0[r * 32768 + t * 512] = (bf16)hp0[r];
    }

    // ============ P2 g1: h_tilde + blend (hides g0 P2 barrier) ============
    POLL1(c1, 8 * ep1);
    STAGE(16384, rhsrc1);
    __syncthreads();
    {
      f32x4 he = {}, ho = {};
      #pragma unroll
      for (int kk = 0; kk < 16; kk += 2) {
        bf16x8 a0 = *(const bf16x8*)(ldsb + 16384 + (fb ^ (kk * 64)));
        bf16x8 a1 = *(const bf16x8*)(ldsb + 16384 + (fb ^ ((kk + 1) * 64)));
        bf16x8 bh0 = *(const bf16x8*)(wh + kk * 32);
        bf16x8 bh1 = *(const bf16x8*)(wh + (kk + 1) * 32);
        he = __builtin_amdgcn_mfma_f32_16x16x32_bf16(a0, bh0, he, 0, 0, 0);
        ho = __builtin_amdgcn_mfma_f32_16x16x32_bf16(a1, bh1, ho, 0, 0, 0);
      }
      #pragma unroll
      for (int r = 0; r < 4; ++r) {
        float ht = tanhf(he[r] + ho[r] + xh1[r]);
        hp1[r] = hp1[r] + zf1[r] * (ht - hp1[r]);
      }
      if (t + 1 < T_SZ) {
        GST2(hst1, "0", hp1[0]); GST2(hst1, "1024", hp1[1]);
        GST2(hst1, "2048", hp1[2]); GST2(hst1, "3072", hp1[3]);
        WAITV;
        __syncthreads();
        ++ep1; ARR(c1);
      }
      #pragma unroll
      for (int r = 0; r < 4; ++r) hsst1[r * 32768 + t * 512] = (bf16)hp1[r];
    }

    if (t + 1 < T_SZ) {
      // deferred: next-step X prefetch during the end-of-step polls
      #pragma unroll
      for (int r = 0; r < 4; ++r) {
        xz0[r] = xb0[r * 98304 + (t + 1) * 1536];
        xr0[r] = xb0[r * 98304 + (t + 1) * 1536 + 512];
        xz1[r] = xb1[r * 98304 + (t + 1) * 1536];
        xr1[r] = xb1[r * 98304 + (t + 1) * 1536 + 512];
      }
      // dual poll: lane 0 waits c0, lane 1 waits c1 (one divergent loop)
      if (tid < 2) {
        int* c  = (tid == 0) ? c0 : c1;
        int  tg = 8 * ((tid == 0) ? ep0 : ep1);
        while (__hip_atomic_load(c, __ATOMIC_RELAXED, __HIP_MEMORY_SCOPE_AGENT) < tg)
          __builtin_amdgcn_s_sleep(1);
      }
      __syncthreads();
    }
  }
#undef STAGE
#undef ARR
#undef POLL1
}

// ---------------- host ----------------
extern "C" void kernel_launch(void* const* d_in, const int* in_sizes, int n_in,
                              void* d_out, int out_size, void* d_ws, size_t ws_size,
                              hipStream_t stream) {
  const float* feat = (const float*)d_in[0];
  const int*   caps = (const int*)d_in[1];
  const float* emb  = (const float*)d_in[2];
  const float* Wz_w = (const float*)d_in[3];
  const float* Wz_b = (const float*)d_in[4];
  const float* Wr_w = (const float*)d_in[5];
  const float* Wr_b = (const float*)d_in[6];
  const float* Wh_w = (const float*)d_in[7];
  const float* Wh_b = (const float*)d_in[8];
  const float* fc_w = (const float*)d_in[9];
  const float* fc_b = (const float*)d_in[10];
  float* out = (float*)d_out;

  char* ws = (char*)d_ws;
  float* X_all = (float*)(ws + 0);              // 12,582,912
  bf16*  h_g   = (bf16*) (ws + 12582912);       // 32,768
  bf16*  rh_g  = (bf16*) (ws + 12615680);       // 32,768
  bf16*  hs    = (bf16*) (ws + 12648448);       // 2,097,152
  bf16*  Whp   = (bf16*) (ws + 14745600);       // 1,572,864
  int*   ctr   = (int*)  (ws + 16318464);       // 512 B flag area
  bf16*  fcw16 = (bf16*) (ws + 16318976);       // 32,768,000 -> end 49,086,976
  const bool cvt_fc = (ws_size >= (size_t)49087000);

  prep_k<<<dim3(384), dim3(256), 0, stream>>>(feat, h_g, ctr, Wz_w, Wr_w, Wh_w, Whp);

  // fused x-projections (192 gemm blocks) + fc_w cvt (128 blocks)
  gemm_bt<1, true><<<dim3(cvt_fc ? 320 : 192), dim3(256), 0, stream>>>(
      nullptr, caps, emb, Wz_w, Wr_w, Wh_w, 1024, Wz_b, Wr_b, Wh_b,
      X_all, 1536, 512, 16, 192, fc_w, fcw16);

  gru_rec<<<dim3(8), dim3(256), 0, stream>>>(
      X_all, Whp, Whp + 262144, Whp + 524288, feat, h_g, rh_g, hs, ctr);

  // logits: hs[2048,512](bf16) @ fc_w[32000,512]^T + fc_b -> f32 out
  if (cvt_fc)
    gemm_bt<0, false><<<dim3(4000), dim3(256), 0, stream>>>(
        hs, nullptr, nullptr, fcw16, nullptr, nullptr, 512, fc_b, nullptr, nullptr,
        out, 32000, 512, 16, 4000, nullptr, nullptr);
  else
    gemm_bt<0, true><<<dim3(4000), dim3(256), 0, stream>>>(
        hs, nullptr, nullptr, fc_w, nullptr, nullptr, 512, fc_b, nullptr, nullptr,
        out, 32000, 512, 16, 4000, nullptr, nullptr);
}

// Round 11
// 706.904 us; speedup vs baseline: 1.7647x; 1.7647x over previous
//
#include <hip/hip_runtime.h>
#include <hip/hip_bf16.h>

typedef __bf16 bf16;
typedef __bf16 bf16x8 __attribute__((ext_vector_type(8)));
typedef float f32x4 __attribute__((ext_vector_type(4)));
typedef unsigned int u32x4 __attribute__((ext_vector_type(4)));

#define B_SZ 32
#define T_SZ 64
#define H_SZ 512
#define V_SZ 32000
#define NWG_REC 8
#define NTILES 250
#define MTILES 16

__device__ __forceinline__ float sigmoidf_(float v) { return 1.0f / (1.0f + expf(-v)); }

__device__ __forceinline__ bf16x8 cvt8(const float* __restrict__ p) {
  float4 a = *(const float4*)p;
  float4 b = *(const float4*)(p + 4);
  bf16x8 o;
  o[0] = (bf16)a.x; o[1] = (bf16)a.y; o[2] = (bf16)a.z; o[3] = (bf16)a.w;
  o[4] = (bf16)b.x; o[5] = (bf16)b.y; o[6] = (bf16)b.z; o[7] = (bf16)b.w;
  return o;
}

// ---- LLC-coherent primitives (bypass L1/L2 via sc0 sc1) ----
#define GLD(dst, base, off) \
  asm volatile("global_load_dwordx4 %0, %1, off offset:" off " sc0 sc1" \
               : "=v"(dst) : "v"(base))
#define GST2(base, off, val) do { \
  unsigned int w_ = (unsigned int)__builtin_bit_cast(unsigned short, (bf16)(val)); \
  asm volatile("global_store_short %0, %1, off offset:" off " sc0 sc1" \
               :: "v"(base), "v"(w_) : "memory"); \
} while (0)
#define WAITV  asm volatile("s_waitcnt vmcnt(0)" ::: "memory")
#define SCHEDB __builtin_amdgcn_sched_barrier(0)

// ---------------- prep: h0 init, flags, Wz/Wr/Wh h-part extract+cvt ----------------
__global__ void prep_k(const float* __restrict__ feat, bf16* __restrict__ h_g,
                       int* __restrict__ ctr,
                       const float* __restrict__ Wz, const float* __restrict__ Wr,
                       const float* __restrict__ Wh, bf16* __restrict__ dst) {
  int i = blockIdx.x * blockDim.x + threadIdx.x;   // 98304 threads
  int w = i >> 15;
  int rem = i & 32767;
  int n = rem >> 6;
  int k8 = (rem & 63) * 8;
  const float* W = (w == 0) ? Wz : (w == 1) ? Wr : Wh;
  *(bf16x8*)(dst + (long)w * 262144 + n * 512 + k8) = cvt8(W + (long)n * 1024 + 512 + k8);
  if (i < B_SZ * H_SZ) h_g[i] = (bf16)feat[i];
  if (i < 128) ctr[i] = 0;
}

// ---------------- x-proj GEMM (128x128, 256 thr) + fused fc_w cvt blocks ----------------
__global__ __launch_bounds__(256) void xproj_k(
    const int* __restrict__ caps, const float* __restrict__ emb,
    const float* __restrict__ B0, const float* __restrict__ B1, const float* __restrict__ B2,
    const float* __restrict__ bias0, const float* __restrict__ bias1, const float* __restrict__ bias2,
    float* __restrict__ C, int gemm_blocks,
    const float* __restrict__ fcw_src, bf16* __restrict__ fcw_dst)
{
  __shared__ __align__(16) bf16 lA[128 * 32];
  __shared__ __align__(16) bf16 lB[128 * 32];
  const int tid = threadIdx.x;

  if ((int)blockIdx.x >= gemm_blocks) {   // fc_w f32->bf16 cvt
    long base = ((long)(blockIdx.x - gemm_blocks) * 256 + tid) * 8;
    const long stride = (long)128 * 256 * 8;
    for (long i = base; i < (long)V_SZ * H_SZ; i += stride)
      *(bf16x8*)(fcw_dst + i) = cvt8(fcw_src + i);
    return;
  }

  const int lane = tid & 63;
  const int l15  = lane & 15;
  const int kb8  = (lane >> 4) * 8;
  const int wid  = tid >> 6;
  const int wm   = wid >> 1, wn = wid & 1;
  const int wg   = blockIdx.x;
  const int mtile = wg % 16, ntile = wg / 16;
  const int m0 = mtile * 128, n0 = ntile * 128;

  int wsel = n0 >> 9;
  const float* Bv   = wsel == 0 ? B0 : wsel == 1 ? B1 : B2;
  const float* bias = wsel == 0 ? bias0 : wsel == 1 ? bias1 : bias2;
  int nb = n0 & 511;

  f32x4 acc[4][4] = {};

  for (int k0 = 0; k0 < 512; k0 += 32) {
    #pragma unroll
    for (int j = 0; j < 2; ++j) {
      int c = j * 256 + tid;
      int row = c >> 2;
      int kc = (c & 3) * 8;
      *(bf16x8*)&lA[row * 32 + kc] = cvt8(emb + (long)caps[m0 + row] * 512 + k0 + kc);
      *(bf16x8*)&lB[row * 32 + kc] = cvt8(Bv + (long)(nb + row) * 1024 + k0 + kc);
    }
    __syncthreads();
    bf16x8 af[4], bfr[4];
    #pragma unroll
    for (int mf = 0; mf < 4; ++mf)
      af[mf] = *(const bf16x8*)&lA[(wm * 64 + mf * 16 + l15) * 32 + kb8];
    #pragma unroll
    for (int nf = 0; nf < 4; ++nf)
      bfr[nf] = *(const bf16x8*)&lB[(wn * 64 + nf * 16 + l15) * 32 + kb8];
    #pragma unroll
    for (int mf = 0; mf < 4; ++mf)
      #pragma unroll
      for (int nf = 0; nf < 4; ++nf)
        acc[mf][nf] = __builtin_amdgcn_mfma_f32_16x16x32_bf16(af[mf], bfr[nf], acc[mf][nf], 0, 0, 0);
    __syncthreads();
  }

  #pragma unroll
  for (int mf = 0; mf < 4; ++mf)
    #pragma unroll
    for (int nf = 0; nf < 4; ++nf)
      #pragma unroll
      for (int r = 0; r < 4; ++r) {
        int row = m0 + wm * 64 + mf * 16 + (lane >> 4) * 4 + r;
        int lc  = wn * 64 + nf * 16 + l15;
        C[(long)row * 1536 + n0 + lc] = acc[mf][nf][r] + bias[nb + lc];
      }
}

// ---------------- FUSED: persistent GRU recurrence (blocks 0..7, R4-verbatim) +
//                  logits GEMM workers (blocks 8.., gated on recurrence progress) ----
// Rec barrier counter ctr[0] doubles as progress flag: after P2 of step t, ctr >= 16*(t+1)
// and all hs stores for step t are drained to LLC (sc0sc1). hs is t-major: row = t*32+b.
__global__ __launch_bounds__(512, 2) void fused_k(
    const float* __restrict__ X,
    const bf16* __restrict__ Wzh, const bf16* __restrict__ Wrh, const bf16* __restrict__ Whh,
    const float* __restrict__ feat,
    bf16* __restrict__ h_g, bf16* __restrict__ rh_g,
    bf16* __restrict__ hs, int* __restrict__ ctr,
    const bf16* __restrict__ fcw16, const float* __restrict__ fcw_f32,
    const float* __restrict__ fc_b, float* __restrict__ out, int use_bf16B)
{
  __shared__ __align__(16) char smem[16384];
  const int tid  = threadIdx.x;                   // 0..511
  const int bid  = blockIdx.x;
  const int lane = tid & 63;
  const int l15  = lane & 15;

  if (bid < NWG_REC) {
    // ================= R4 recurrence (512 us proven) =================
    char* ldsb = smem;
    const int u    = bid * 8 + (tid >> 6);        // wave 0..63
    const int kb   = (lane >> 4) * 8;
    const int rq   = (lane >> 4) * 4;
    const int b0   = (u >> 5) * 16;
    const int gcol = (u & 31) * 16 + l15;

    u32x4 Bz[16], Br[16], Bh[16];
    #pragma unroll
    for (int kk = 0; kk < 16; ++kk) {
      Bz[kk] = *(const u32x4*)(Wzh + (long)gcol * 512 + kk * 32 + kb);
      Br[kk] = *(const u32x4*)(Wrh + (long)gcol * 512 + kk * 32 + kb);
      Bh[kk] = *(const u32x4*)(Whh + (long)gcol * 512 + kk * 32 + kb);
    }
    #pragma unroll
    for (int kk = 0; kk < 16; ++kk)
      asm volatile("" : "+v"(Bz[kk]), "+v"(Br[kk]), "+v"(Bh[kk]));

    float hprev[4];
    #pragma unroll
    for (int r = 0; r < 4; ++r) hprev[r] = feat[(b0 + rq + r) * 512 + gcol];

    const float* xb = X + (long)(b0 + rq) * 64 * 1536 + gcol;
    float xz[4], xr[4];
    #pragma unroll
    for (int r = 0; r < 4; ++r) {
      xz[r] = xb[r * 98304];
      xr[r] = xb[r * 98304 + 512];
    }

    const int srow0 = tid >> 6;
    const int soff0 = (tid * 16) ^ ((srow0 & 7) << 4);
    const int soff1 = (8192 + tid * 16) ^ ((srow0 & 7) << 4);
    const int fbase = (l15 * 1024 + (lane >> 4) * 16) ^ ((l15 & 7) << 4);

    bf16* rhst = rh_g + (b0 + rq) * 512 + gcol;
    bf16* hst  = h_g  + (b0 + rq) * 512 + gcol;

    int epoch = 0;
    for (int t = 0; t < T_SZ; ++t) {
      // ---- phase 1: stage h -> LDS; z (regs) + r -> rh ----
      {
        const bf16* src = h_g + b0 * 512;
        u32x4 v0, v1;
        GLD(v0, src + tid * 8, "0");
        GLD(v1, src + 4096 + tid * 8, "0");
        WAITV;
        SCHEDB;
        *(u32x4*)(ldsb + soff0) = v0;
        *(u32x4*)(ldsb + soff1) = v1;
      }
      __syncthreads();
      f32x4 ze = {}, re = {};
      #pragma unroll
      for (int kk = 0; kk < 16; ++kk) {
        bf16x8 a = *(const bf16x8*)(ldsb + (fbase ^ (kk * 64)));
        ze = __builtin_amdgcn_mfma_f32_16x16x32_bf16(a, __builtin_bit_cast(bf16x8, Bz[kk]), ze, 0, 0, 0);
        re = __builtin_amdgcn_mfma_f32_16x16x32_bf16(a, __builtin_bit_cast(bf16x8, Br[kk]), re, 0, 0, 0);
      }
      float xh[4];
      #pragma unroll
      for (int r = 0; r < 4; ++r) xh[r] = xb[r * 98304 + t * 1536 + 1024];
      f32x4 zf;
      {
        float r0 = sigmoidf_(re[0] + xr[0]) * hprev[0];
        float r1 = sigmoidf_(re[1] + xr[1]) * hprev[1];
        float r2 = sigmoidf_(re[2] + xr[2]) * hprev[2];
        float r3 = sigmoidf_(re[3] + xr[3]) * hprev[3];
        GST2(rhst, "0", r0); GST2(rhst, "1024", r1); GST2(rhst, "2048", r2); GST2(rhst, "3072", r3);
        #pragma unroll
        for (int r = 0; r < 4; ++r) zf[r] = sigmoidf_(ze[r] + xz[r]);
      }
      ++epoch;
      // gridbar
      asm volatile("s_waitcnt vmcnt(0) lgkmcnt(0)" ::: "memory");
      __syncthreads();
      if (tid == 0) {
        __hip_atomic_fetch_add(ctr, 1, __ATOMIC_RELAXED, __HIP_MEMORY_SCOPE_AGENT);
        while (__hip_atomic_load(ctr, __ATOMIC_RELAXED, __HIP_MEMORY_SCOPE_AGENT) < NWG_REC * epoch)
          __builtin_amdgcn_s_sleep(1);
      }
      __syncthreads();

      // ---- phase 2: stage rh -> LDS; h_tilde + blend; h + hs(t-major) -> LLC ----
      {
        const bf16* src = rh_g + b0 * 512;
        u32x4 v0, v1;
        GLD(v0, src + tid * 8, "0");
        GLD(v1, src + 4096 + tid * 8, "0");
        WAITV;
        SCHEDB;
        *(u32x4*)(ldsb + soff0) = v0;
        *(u32x4*)(ldsb + soff1) = v1;
      }
      __syncthreads();
      f32x4 he = {};
      #pragma unroll
      for (int kk = 0; kk < 16; ++kk) {
        bf16x8 a = *(const bf16x8*)(ldsb + (fbase ^ (kk * 64)));
        he = __builtin_amdgcn_mfma_f32_16x16x32_bf16(a, __builtin_bit_cast(bf16x8, Bh[kk]), he, 0, 0, 0);
      }
      if (t + 1 < T_SZ) {
        #pragma unroll
        for (int r = 0; r < 4; ++r) {
          xz[r] = xb[r * 98304 + (t + 1) * 1536];
          xr[r] = xb[r * 98304 + (t + 1) * 1536 + 512];
        }
      }
      bf16* ph = hs + (long)(t * 32 + b0 + rq) * 512 + gcol;  // t-major
      #pragma unroll
      for (int r = 0; r < 4; ++r) {
        float ht = tanhf(he[r] + xh[r]);
        float hn = hprev[r] + zf[r] * (ht - hprev[r]);        // (1-z)h + z*ht
        hprev[r] = hn;
      }
      GST2(hst, "0", hprev[0]); GST2(hst, "1024", hprev[1]);
      GST2(hst, "2048", hprev[2]); GST2(hst, "3072", hprev[3]);
      GST2(ph, "0", hprev[0]); GST2(ph, "1024", hprev[1]);
      GST2(ph, "2048", hprev[2]); GST2(ph, "3072", hprev[3]);
      ++epoch;
      // gridbar (drains h + hs stores before arrival => ctr is a valid hs-progress flag)
      asm volatile("s_waitcnt vmcnt(0) lgkmcnt(0)" ::: "memory");
      __syncthreads();
      if (tid == 0) {
        __hip_atomic_fetch_add(ctr, 1, __ATOMIC_RELAXED, __HIP_MEMORY_SCOPE_AGENT);
        while (__hip_atomic_load(ctr, __ATOMIC_RELAXED, __HIP_MEMORY_SCOPE_AGENT) < NWG_REC * epoch)
          __builtin_amdgcn_s_sleep(1);
      }
      __syncthreads();
    }
    return;
  }

  // ================= logits worker: 128x128 tile, 8 waves, gated on ctr =================
  const int lwg   = bid - NWG_REC;
  const int mtile = lwg / NTILES;       // mtile-slow: early blocks take early timesteps
  const int ntile = lwg % NTILES;
  const int m0 = mtile * 128, n0 = ntile * 128;

  if (tid == 0) {
    const int tgt = 64 * (mtile + 1);   // steps 0..4*mtile+3 complete
    while (__hip_atomic_load(ctr, __ATOMIC_RELAXED, __HIP_MEMORY_SCOPE_AGENT) < tgt)
      __builtin_amdgcn_s_sleep(2);
  }
  __syncthreads();

  bf16* lA = (bf16*)smem;
  bf16* lB = (bf16*)(smem + 8192);
  const int kb8  = (lane >> 4) * 8;
  const int wid  = tid >> 6;            // 0..7
  const int wm   = wid >> 1;            // 0..3 -> 32 rows each
  const int wn   = wid & 1;             // 0..1 -> 64 cols each
  const int arow = tid >> 2;
  const int akc  = (tid & 3) * 8;

  f32x4 acc[2][4] = {};

  for (int k0 = 0; k0 < 512; k0 += 32) {
    u32x4 av;
    GLD(av, hs + (long)(m0 + arow) * 512 + k0 + akc, "0");   // LLC-fresh (sc0sc1-written)
    bf16x8 bv;
    if (use_bf16B) bv = *(const bf16x8*)(fcw16 + (long)(n0 + arow) * 512 + k0 + akc);
    else           bv = cvt8(fcw_f32 + (long)(n0 + arow) * 512 + k0 + akc);
    WAITV;
    SCHEDB;
    *(u32x4*)&lA[arow * 32 + akc] = av;
    *(bf16x8*)&lB[arow * 32 + akc] = bv;
    __syncthreads();
    bf16x8 af[2], bfr[4];
    #pragma unroll
    for (int mf = 0; mf < 2; ++mf)
      af[mf] = *(const bf16x8*)&lA[(wm * 32 + mf * 16 + l15) * 32 + kb8];
    #pragma unroll
    for (int nf = 0; nf < 4; ++nf)
      bfr[nf] = *(const bf16x8*)&lB[(wn * 64 + nf * 16 + l15) * 32 + kb8];
    #pragma unroll
    for (int mf = 0; mf < 2; ++mf)
      #pragma unroll
      for (int nf = 0; nf < 4; ++nf)
        acc[mf][nf] = __builtin_amdgcn_mfma_f32_16x16x32_bf16(af[mf], bfr[nf], acc[mf][nf], 0, 0, 0);
    __syncthreads();
  }

  // epilogue: remap t-major row rr = t*32+b -> out row b*64+t
  #pragma unroll
  for (int mf = 0; mf < 2; ++mf)
    #pragma unroll
    for (int nf = 0; nf < 4; ++nf) {
      int col = n0 + wn * 64 + nf * 16 + l15;
      float bias_v = fc_b[col];
      #pragma unroll
      for (int r = 0; r < 4; ++r) {
        int rr = m0 + wm * 32 + mf * 16 + (lane >> 4) * 4 + r;
        int tt = rr >> 5, b = rr & 31;
        out[(long)(b * 64 + tt) * 32000 + col] = acc[mf][nf][r] + bias_v;
      }
    }
}

// ---------------- host ----------------
extern "C" void kernel_launch(void* const* d_in, const int* in_sizes, int n_in,
                              void* d_out, int out_size, void* d_ws, size_t ws_size,
                              hipStream_t stream) {
  const float* feat = (const float*)d_in[0];
  const int*   caps = (const int*)d_in[1];
  const float* emb  = (const float*)d_in[2];
  const float* Wz_w = (const float*)d_in[3];
  const float* Wz_b = (const float*)d_in[4];
  const float* Wr_w = (const float*)d_in[5];
  const float* Wr_b = (const float*)d_in[6];
  const float* Wh_w = (const float*)d_in[7];
  const float* Wh_b = (const float*)d_in[8];
  const float* fc_w = (const float*)d_in[9];
  const float* fc_b = (const float*)d_in[10];
  float* out = (float*)d_out;

  char* ws = (char*)d_ws;
  float* X_all = (float*)(ws + 0);              // 12,582,912
  bf16*  h_g   = (bf16*) (ws + 12582912);       // 32,768
  bf16*  rh_g  = (bf16*) (ws + 12615680);       // 32,768
  bf16*  hs    = (bf16*) (ws + 12648448);       // 2,097,152 (t-major: row = t*32+b)
  bf16*  Whp   = (bf16*) (ws + 14745600);       // 1,572,864
  int*   ctr   = (int*)  (ws + 16318464);       // 512 B flag area
  bf16*  fcw16 = (bf16*) (ws + 16318976);       // 32,768,000 -> end 49,086,976
  const bool cvt_fc = (ws_size >= (size_t)49087000);

  prep_k<<<dim3(384), dim3(256), 0, stream>>>(feat, h_g, ctr, Wz_w, Wr_w, Wh_w, Whp);

  // x-projections (192 gemm blocks) + fc_w cvt (128 blocks)
  xproj_k<<<dim3(cvt_fc ? 320 : 192), dim3(256), 0, stream>>>(
      caps, emb, Wz_w, Wr_w, Wh_w, Wz_b, Wr_b, Wh_b, X_all, 192, fc_w, fcw16);

  // fused: 8 recurrence wgs + 4000 progress-gated logits wgs
  fused_k<<<dim3(NWG_REC + MTILES * NTILES), dim3(512), 0, stream>>>(
      X_all, Whp, Whp + 262144, Whp + 524288, feat, h_g, rh_g, hs, ctr,
      fcw16, fc_w, fc_b, out, cvt_fc ? 1 : 0);
}